// Round 5
// baseline (141.246 us; speedup 1.0000x reference)
//
#include <hip/hip_runtime.h>
#include <math.h>

#define NTOT 4096
#define BSZH 2048
#define DIMK 256
#define GY   32            // 4096/128 column tiles

typedef __bf16 bf16x8 __attribute__((ext_vector_type(8)));
typedef __bf16 bf16x4 __attribute__((ext_vector_type(4)));
typedef float  f32x4  __attribute__((ext_vector_type(4)));

__global__ void k_zero(float* out) { out[0] = 0.0f; }

// fp32 -> bf16 convert + row squared norms. One wave per row, 4 rows/block.
__global__ __launch_bounds__(256) void k_prep(const float* __restrict__ f,
                                              __bf16* __restrict__ fb,
                                              float* __restrict__ sq) {
    int row  = blockIdx.x * 4 + (threadIdx.x >> 6);
    int lane = threadIdx.x & 63;
    float4 v = *(const float4*)(f + row * DIMK + lane * 4);
    bf16x4 pk;
    pk[0] = (__bf16)v.x; pk[1] = (__bf16)v.y; pk[2] = (__bf16)v.z; pk[3] = (__bf16)v.w;
    *(bf16x4*)(fb + row * DIMK + lane * 4) = pk;
    float s = v.x*v.x + v.y*v.y + v.z*v.z + v.w*v.w;
    #pragma unroll
    for (int off = 32; off > 0; off >>= 1) s += __shfl_xor(s, off, 64);
    if (lane == 0) sq[row] = s;
}

// 128x128 tile per block: bf16 MFMA gram (K=256) + fused sim epilogue +
// per-row {max, sum exp(sim), sum pos sim, npos} partials (shift-free).
__global__ __launch_bounds__(256) void k_main(const __bf16* __restrict__ fb,
                                              const int* __restrict__ labels,
                                              const float* __restrict__ sq,
                                              float4* __restrict__ part) {
    const int tid  = threadIdx.x;
    const int wid  = tid >> 6, lane = tid & 63;
    const int l15  = lane & 15, lg = lane >> 4;
    const int wr   = wid >> 1, wc = wid & 1;
    const int rowb = blockIdx.x * 128 + wr * 64;
    const int colb = blockIdx.y * 128 + wc * 64;

    f32x4 acc[4][4];
    #pragma unroll
    for (int i = 0; i < 4; ++i)
        #pragma unroll
        for (int j = 0; j < 4; ++j) acc[i][j] = (f32x4){0.f, 0.f, 0.f, 0.f};

    // A-frag: lane holds A[row = l&15][k = (l>>4)*8 + 0..7]
    // B-frag: lane holds B[k = (l>>4)*8 + 0..7][col = l&15] = f[col][k]
    const __bf16* pa0 = fb + (size_t)(rowb + l15) * DIMK + lg * 8;
    const __bf16* pb0 = fb + (size_t)(colb + l15) * DIMK + lg * 8;
    const __bf16* pA[4]; const __bf16* pB[4];
    #pragma unroll
    for (int i = 0; i < 4; ++i) { pA[i] = pa0 + i * 16 * DIMK; pB[i] = pb0 + i * 16 * DIMK; }

    #pragma unroll
    for (int k0 = 0; k0 < DIMK; k0 += 32) {
        bf16x8 av[4], bv[4];
        #pragma unroll
        for (int i = 0; i < 4; ++i) {
            av[i] = *(const bf16x8*)(pA[i] + k0);
            bv[i] = *(const bf16x8*)(pB[i] + k0);
        }
        #pragma unroll
        for (int i = 0; i < 4; ++i)
            #pragma unroll
            for (int j = 0; j < 4; ++j)
                acc[i][j] = __builtin_amdgcn_mfma_f32_16x16x32_bf16(av[i], bv[j], acc[i][j], 0, 0, 0);
    }

    // ---- epilogue ----
    float cb2[4], cb2p[4], cb01[4], cinv[4]; int clab[4], ccol[4];
    #pragma unroll
    for (int j = 0; j < 4; ++j) {
        int col = colb + j * 16 + l15;
        float b2 = sq[col];
        ccol[j] = col; cb2[j] = b2;
        cb2p[j] = fmaf(0.01f, b2, 1.0f);      // 1 + c*b2
        cb01[j] = 0.01f * b2;                 // c*b2
        cinv[j] = __frsqrt_rn(fmaxf(b2, 1e-24f));
        clab[j] = labels[col & (BSZH - 1)];
    }

    float stM[4][4], stT[4][4], stP[4][4], stN[4][4];
    #pragma unroll
    for (int i = 0; i < 4; ++i)
        #pragma unroll
        for (int t = 0; t < 4; ++t) { stM[i][t] = -INFINITY; stT[i][t] = 0.f; stP[i][t] = 0.f; stN[i][t] = 0.f; }

    #pragma unroll
    for (int i = 0; i < 4; ++i) {
        float ra2[4], rinv[4], Bv[4], B2v[4]; int rlab[4], rrow[4];
        #pragma unroll
        for (int t = 0; t < 4; ++t) {
            int row = rowb + i * 16 + lg * 4 + t;
            float a2 = sq[row];
            rrow[t] = row; ra2[t] = a2;
            rinv[t] = __frsqrt_rn(fmaxf(a2, 1e-24f));
            rlab[t] = labels[row & (BSZH - 1)];
            float B = fmaf(-0.01f, a2, 1.0f);   // 1 - c*a2
            Bv[t] = B; B2v[t] = B * B;
        }
        #pragma unroll
        for (int j = 0; j < 4; ++j) {
            f32x4 a = acc[i][j];
            #pragma unroll
            for (int t = 0; t < 4; ++t) {
                float g   = a[t];
                float A   = fmaf(-0.02f, g, cb2p[j]);          // 1 + 2c*ab + c*b2, ab=-g
                float den = fmaf(-cb01[j], Bv[t], A);          // 1 + 2c*ab + c^2*a2*b2
                float AB  = A * Bv[t];
                float num = fmaf(ra2[t] * A, A, fmaf(-(g + g), AB, cb2[j] * B2v[t]));
                float s   = sqrtf(fmaxf(num, 1e-12f));
                float h   = 0.1f * s;                          // sqrt_c * dist * den
                // atanh(x) = 0.5*ln((1+x)/(1-x)); x = h/den (cap at 1-1e-5 never hits: x<=~0.25)
                float r    = __fdividef(den + h, den - h);
                float u    = fmaf(-6.93147181f, __log2f(r), g * rinv[t] * cinv[j]); // dsim + ang
                float sim  = 7.14285714f * u;                  // (0.5*dsim+0.5*ang)/0.07
                float e    = __expf(sim);
                bool  dg   = (rrow[t] == ccol[j]);
                stM[i][t]  = fmaxf(stM[i][t], sim);            // max includes diag (ref semantics)
                stT[i][t] += dg ? 0.f : e;
                bool  pos  = (!dg) && (rlab[t] == clab[j]);
                stP[i][t] += pos ? sim : 0.f;
                stN[i][t] += pos ? 1.f : 0.f;
            }
        }
    }

    // butterfly reduce across the 16 column-lanes (l15); stays within 16-lane group
    #pragma unroll
    for (int i = 0; i < 4; ++i)
        #pragma unroll
        for (int t = 0; t < 4; ++t) {
            float M = stM[i][t], T = stT[i][t], P = stP[i][t], N = stN[i][t];
            #pragma unroll
            for (int m = 1; m < 16; m <<= 1) {
                M = fmaxf(M, __shfl_xor(M, m, 64));
                T += __shfl_xor(T, m, 64);
                P += __shfl_xor(P, m, 64);
                N += __shfl_xor(N, m, 64);
            }
            stM[i][t] = M; stT[i][t] = T; stP[i][t] = P; stN[i][t] = N;
        }

    __shared__ float red[2][2][64][4];   // [wr][wc][row_local][M,T,P,N]
    if (l15 == 0) {
        #pragma unroll
        for (int i = 0; i < 4; ++i)
            #pragma unroll
            for (int t = 0; t < 4; ++t) {
                int rl = i * 16 + lg * 4 + t;
                red[wr][wc][rl][0] = stM[i][t];
                red[wr][wc][rl][1] = stT[i][t];
                red[wr][wc][rl][2] = stP[i][t];
                red[wr][wc][rl][3] = stN[i][t];
            }
    }
    __syncthreads();
    if (tid < 128) {
        int w = tid >> 6, rl = tid & 63;
        float M = fmaxf(red[w][0][rl][0], red[w][1][rl][0]);
        float T = red[w][0][rl][1] + red[w][1][rl][1];
        float P = red[w][0][rl][2] + red[w][1][rl][2];
        float N = red[w][0][rl][3] + red[w][1][rl][3];
        part[(size_t)(blockIdx.x * 128 + w * 64 + rl) * GY + blockIdx.y] = make_float4(M, T, P, N);
    }
}

// combine 32 column-tile partials per row; loss = mean over rows of
//   log(T + 1e-10*e^M) - P/Np     (shift-invariance of logits folded in)
__global__ void k_final(const float4* __restrict__ part, float* __restrict__ out) {
    int row = blockIdx.x * 256 + threadIdx.x;
    float M = -INFINITY, T = 0.f, P = 0.f, N = 0.f;
    #pragma unroll
    for (int k = 0; k < GY; ++k) {
        float4 p = part[(size_t)row * GY + k];
        M = fmaxf(M, p.x); T += p.y; P += p.z; N += p.w;
    }
    float denom = (N < 1e-6f) ? 1.f : N;
    float v = (__logf(fmaf(1e-10f, __expf(M), T)) - P / denom) * (1.0f / NTOT);
    #pragma unroll
    for (int off = 32; off > 0; off >>= 1) v += __shfl_xor(v, off, 64);
    __shared__ float wsum[4];
    int wd = threadIdx.x >> 6, lane = threadIdx.x & 63;
    if (lane == 0) wsum[wd] = v;
    __syncthreads();
    if (threadIdx.x == 0) atomicAdd(out, wsum[0] + wsum[1] + wsum[2] + wsum[3]);
}

extern "C" void kernel_launch(void* const* d_in, const int* in_sizes, int n_in,
                              void* d_out, int out_size, void* d_ws, size_t ws_size,
                              hipStream_t stream) {
    const float* f      = (const float*)d_in[0];
    const int*   labels = (const int*)d_in[1];
    float* out = (float*)d_out;

    __bf16* fb   = (__bf16*)d_ws;                                  // 2 MiB
    float*  sq   = (float*)((char*)d_ws + (size_t)NTOT * DIMK * 2);          // 16 KiB
    float4* part = (float4*)((char*)d_ws + (size_t)NTOT * DIMK * 2 + 65536); // 2 MiB

    k_zero <<<dim3(1),        dim3(1),   0, stream>>>(out);
    k_prep <<<dim3(NTOT / 4), dim3(256), 0, stream>>>(f, fb, sq);
    k_main <<<dim3(NTOT / 128, NTOT / 128), dim3(256), 0, stream>>>(fb, labels, sq, part);
    k_final<<<dim3(NTOT / 256), dim3(256), 0, stream>>>(part, out);
}